// Round 2
// baseline (6100.632 us; speedup 1.0000x reference)
//
#include <hip/hip_runtime.h>
#include <cstdint>

// LSTM: SEQ=512, B=64, IN=H=1024. fp32 in/out, bf16 MFMA compute.
// Round 2: persistent-per-chunk recurrence kernel. W_hh lives in VGPRs
// (128 regs/lane across the whole grid = 8 MB), h broadcast per b-group via
// global bf16 double buffer + custom 64-WG agent-scope barrier (4 independent
// b-groups). Replaces 512 lstm_step launches with 4 lstm_recur launches.

typedef __bf16 bf16x8 __attribute__((ext_vector_type(8)));
typedef __bf16 bf16x4 __attribute__((ext_vector_type(4)));
typedef float  floatx4 __attribute__((ext_vector_type(4)));

#define SEQ   512
#define BATCH 64
#define HID   1024
#define GATES 4096
#define TC    128   // time-chunk for x_proj buffer (B*TC*4H fp32 = 128 MB)

__device__ __forceinline__ float fast_sigm(float x) {
  return 1.0f / (1.0f + __expf(-x));
}
__device__ __forceinline__ float fast_tanh(float x) {
  x = fminf(15.0f, fmaxf(-15.0f, x));
  float e = __expf(2.0f * x);
  return (e - 1.0f) / (e + 1.0f);
}

// ---------------- casts / small prep ----------------
__global__ void cast_f32_to_bf16_x4(const float* __restrict__ src,
                                    __bf16* __restrict__ dst, int n4) {
  int i = blockIdx.x * blockDim.x + threadIdx.x;
  if (i < n4) {
    float4 v = reinterpret_cast<const float4*>(src)[i];
    bf16x4 o;
    o[0] = (__bf16)v.x; o[1] = (__bf16)v.y; o[2] = (__bf16)v.z; o[3] = (__bf16)v.w;
    reinterpret_cast<bf16x4*>(dst)[i] = o;
  }
}

__global__ void bias_sum(const float* __restrict__ a, const float* __restrict__ b,
                         float* __restrict__ o) {
  int i = blockIdx.x * blockDim.x + threadIdx.x;
  if (i < GATES) o[i] = a[i] + b[i];
}

// ---------------- phase 1: x_proj chunk GEMM (unchanged from round 1) ------
__global__ __launch_bounds__(256) void gemm_xproj(
    const __bf16* __restrict__ X,    // [B*SEQ][1024] bf16
    const __bf16* __restrict__ W,    // [4096][1024] bf16 (W_ih)
    const float*  __restrict__ bias, // [4096]
    float*        __restrict__ XP,   // [B*TC][4096] fp32
    int t0) {
  __shared__ __bf16 As[128][40];
  __shared__ __bf16 Bs[128][40];

  const int tid  = threadIdx.x;
  const int lane = tid & 63;
  const int w    = tid >> 6;
  const int wm   = w >> 1, wn = w & 1;
  const int mt   = blockIdx.x;           // = batch b (TC==tile_M==128)
  const int n0   = blockIdx.y * 128;
  const long arow0 = (long)mt * 512 + t0;

  floatx4 acc[4][4] = {};

  for (int k0 = 0; k0 < 1024; k0 += 32) {
    __syncthreads();
#pragma unroll
    for (int r = 0; r < 2; ++r) {
      int c = tid + 256 * r;
      int row = c >> 2, c8 = c & 3;
      *reinterpret_cast<uint4*>(&As[row][c8 * 8]) =
          *reinterpret_cast<const uint4*>(&X[(arow0 + row) * 1024 + k0 + c8 * 8]);
      *reinterpret_cast<uint4*>(&Bs[row][c8 * 8]) =
          *reinterpret_cast<const uint4*>(&W[(long)(n0 + row) * 1024 + k0 + c8 * 8]);
    }
    __syncthreads();

    bf16x8 a[4], b[4];
#pragma unroll
    for (int i = 0; i < 4; ++i)
      a[i] = *reinterpret_cast<const bf16x8*>(
          &As[wm * 64 + i * 16 + (lane & 15)][(lane >> 4) * 8]);
#pragma unroll
    for (int j = 0; j < 4; ++j)
      b[j] = *reinterpret_cast<const bf16x8*>(
          &Bs[wn * 64 + j * 16 + (lane & 15)][(lane >> 4) * 8]);
#pragma unroll
    for (int i = 0; i < 4; ++i)
#pragma unroll
      for (int j = 0; j < 4; ++j)
        acc[i][j] = __builtin_amdgcn_mfma_f32_16x16x32_bf16(a[i], b[j], acc[i][j], 0, 0, 0);
  }

#pragma unroll
  for (int i = 0; i < 4; ++i) {
    int mloc = wm * 64 + i * 16 + (lane >> 4) * 4;
#pragma unroll
    for (int j = 0; j < 4; ++j) {
      int n = n0 + wn * 64 + j * 16 + (lane & 15);
      float bn = bias[n];
#pragma unroll
      for (int r = 0; r < 4; ++r)
        XP[(long)(mt * 128 + mloc + r) * 4096 + n] = acc[i][j][r] + bn;
    }
  }
}

// ---------------- phase 2: persistent recurrence over one TC chunk ---------
// Grid (64 jt, 4 bt) x 256 thr. WG owns 16 batches x 16 j x 4 gates.
// Wave w holds W_hh B-fragments for its K-quarter [w*256, w*256+256) in
// 128 VGPRs (loaded once). Per step: stage h b-tile (32 KB) to LDS, 32 MFMAs
// per wave (K-split), fp32 partial-sum exchange in LDS, fused LSTM update,
// then a 64-WG per-b-group barrier (agent-scope atomic arrive + spin).
__global__ __launch_bounds__(256) void lstm_recur(
    const __bf16* __restrict__ Whh,  // [4096][1024] bf16
    const float*  __restrict__ xp,   // chunk [B][TC][4096] fp32 (bias included)
    __bf16* hb0, __bf16* hb1,        // h double buffer [64][1024] bf16
    float*  __restrict__ cst,        // [64][1024] fp32
    float*  __restrict__ out,        // full output buffer
    unsigned* bar,                   // 4 counters, 256B apart, zeroed per call
    int t0) {
  __shared__ __bf16 Hs[16][1032];        // +8 pad: balanced b128 banking
  __shared__ float  Gred[4][4][16][17];  // [wave][gate][b][jl(+1)]

  const int tid  = threadIdx.x;
  const int lane = tid & 63;
  const int w    = tid >> 6;        // K-quarter owner
  const int jt   = blockIdx.x;      // 0..63
  const int bt   = blockIdx.y;      // 0..3
  const int b0   = bt * 16;

  // ---- load W_hh B-fragments into registers (once per chunk launch) ----
  bf16x8 breg[4][8];
  {
    const int n = lane & 15, u = lane >> 4;
#pragma unroll
    for (int g = 0; g < 4; ++g)
#pragma unroll
      for (int q = 0; q < 8; ++q)
        breg[g][q] = *reinterpret_cast<const bf16x8*>(
            &Whh[(long)(g * 1024 + jt * 16 + n) * 1024 + w * 256 + q * 32 + u * 8]);
  }

  // per-thread element ownership for the update: (b0+bth, jt*16+jl)
  const int bth = tid >> 4;
  const int jl  = tid & 15;
  const int j   = jt * 16 + jl;
  float c_reg = cst[(b0 + bth) * 1024 + j];

  unsigned* mybar = bar + bt * 64;  // 256-B padded counters

  for (int tt = 0; tt < TC; ++tt) {
    const int t = t0 + tt;
    const __bf16* hc = (t & 1) ? hb1 : hb0;
    __bf16*       hn = (t & 1) ? hb0 : hb1;

    // prefetch xp gates for this thread (independent of h -> in flight early)
    const float* xr = &xp[((long)(b0 + bth) * TC + tt) * 4096 + j];
    float xq0 = xr[0], xq1 = xr[1024], xq2 = xr[2048], xq3 = xr[3072];

    // stage h b-tile: thread covers row bth, 16B granules {jl + 16k}
    uint4 hv[8];
    {
      const __bf16* src = &hc[(b0 + bth) * 1024 + jl * 8];
#pragma unroll
      for (int k = 0; k < 8; ++k)
        hv[k] = *reinterpret_cast<const uint4*>(&src[k * 128]);
    }
#pragma unroll
    for (int k = 0; k < 8; ++k)
      *reinterpret_cast<uint4*>(&Hs[bth][jl * 8 + k * 128]) = hv[k];
    __syncthreads();

    // MFMA: 16x16x32, K-quarter per wave, B from registers
    floatx4 acc[4] = {};
    {
      const int m = lane & 15, u = lane >> 4;
#pragma unroll
      for (int q = 0; q < 8; ++q) {
        bf16x8 a = *reinterpret_cast<const bf16x8*>(&Hs[m][w * 256 + q * 32 + u * 8]);
#pragma unroll
        for (int g = 0; g < 4; ++g)
          acc[g] = __builtin_amdgcn_mfma_f32_16x16x32_bf16(a, breg[g][q], acc[g], 0, 0, 0);
      }
    }
    // write K-partials: D layout col(n)=lane&15, row(b)=(lane>>4)*4+r
    {
      const int n = lane & 15, u = lane >> 4;
#pragma unroll
      for (int g = 0; g < 4; ++g)
#pragma unroll
        for (int r = 0; r < 4; ++r)
          Gred[w][g][u * 4 + r][n] = acc[g][r];
    }
    __syncthreads();

    // reduce partials + fused LSTM update (one thread per (b,j))
    float gi = Gred[0][0][bth][jl] + Gred[1][0][bth][jl] + Gred[2][0][bth][jl] + Gred[3][0][bth][jl] + xq0;
    float gf = Gred[0][1][bth][jl] + Gred[1][1][bth][jl] + Gred[2][1][bth][jl] + Gred[3][1][bth][jl] + xq1;
    float gg = Gred[0][2][bth][jl] + Gred[1][2][bth][jl] + Gred[2][2][bth][jl] + Gred[3][2][bth][jl] + xq2;
    float go = Gred[0][3][bth][jl] + Gred[1][3][bth][jl] + Gred[2][3][bth][jl] + Gred[3][3][bth][jl] + xq3;

    float c_new = fast_sigm(gf) * c_reg + fast_sigm(gi) * fast_tanh(gg);
    float h_new = fast_sigm(go) * fast_tanh(c_new);
    c_reg = c_new;
    hn[(b0 + bth) * 1024 + j] = (__bf16)h_new;
    out[(long)(b0 + bth) * (SEQ * HID) + (long)t * HID + j] = h_new;
    if (t == SEQ - 1) {
      out[(long)SEQ * BATCH * HID + (b0 + bth) * HID + j] = h_new;               // h_n
      out[(long)SEQ * BATCH * HID + BATCH * HID + (b0 + bth) * HID + j] = c_new; // c_n
    }

    // ---- per-b-group barrier: 64 WGs, monotone counter ----
    __syncthreads();
    if (tid == 0) {
      __hip_atomic_fetch_add(mybar, 1u, __ATOMIC_RELEASE, __HIP_MEMORY_SCOPE_AGENT);
      const unsigned target = 64u * (unsigned)(t + 1);
      while (__hip_atomic_load(mybar, __ATOMIC_RELAXED, __HIP_MEMORY_SCOPE_AGENT) < target)
        __builtin_amdgcn_s_sleep(1);
      (void)__hip_atomic_load(mybar, __ATOMIC_ACQUIRE, __HIP_MEMORY_SCOPE_AGENT);
    }
    __syncthreads();
  }

  cst[(b0 + bth) * 1024 + j] = c_reg;  // persist c across chunk launches
}

// ---------------- host ----------------
extern "C" void kernel_launch(void* const* d_in, const int* in_sizes, int n_in,
                              void* d_out, int out_size, void* d_ws, size_t ws_size,
                              hipStream_t stream) {
  const float* inp = (const float*)d_in[0];
  const float* h0  = (const float*)d_in[1];
  const float* c0  = (const float*)d_in[2];
  const float* Wih = (const float*)d_in[3];
  const float* Whh = (const float*)d_in[4];
  const float* bih = (const float*)d_in[5];
  const float* bhh = (const float*)d_in[6];
  float* out = (float*)d_out;
  char* ws = (char*)d_ws;

  size_t off = 0;
  __bf16* Wih_b = (__bf16*)(ws + off); off += (size_t)GATES * HID * 2;        // 8 MB
  __bf16* Whh_b = (__bf16*)(ws + off); off += (size_t)GATES * HID * 2;        // 8 MB
  __bf16* x_b   = (__bf16*)(ws + off); off += (size_t)SEQ * BATCH * HID * 2;  // 64 MB
  float*  xp    = (float*)(ws + off);  off += (size_t)BATCH * TC * GATES * 4; // 128 MB
  float*  bias  = (float*)(ws + off);  off += (size_t)GATES * 4;
  float*  cst   = (float*)(ws + off);  off += (size_t)BATCH * HID * 4;
  __bf16* hb0   = (__bf16*)(ws + off); off += (size_t)BATCH * HID * 2;
  __bf16* hb1   = (__bf16*)(ws + off); off += (size_t)BATCH * HID * 2;
  unsigned* bar = (unsigned*)(ws + off); off += 4 * 64 * sizeof(unsigned);    // 1 KB
  if (ws_size < off) return;

  int n4;
  n4 = GATES * HID / 4;
  cast_f32_to_bf16_x4<<<(n4 + 255) / 256, 256, 0, stream>>>(Wih, Wih_b, n4);
  cast_f32_to_bf16_x4<<<(n4 + 255) / 256, 256, 0, stream>>>(Whh, Whh_b, n4);
  n4 = SEQ * BATCH * HID / 4;
  cast_f32_to_bf16_x4<<<(n4 + 255) / 256, 256, 0, stream>>>(inp, x_b, n4);
  n4 = BATCH * HID / 4;
  cast_f32_to_bf16_x4<<<(n4 + 255) / 256, 256, 0, stream>>>(h0, hb0, n4);
  bias_sum<<<GATES / 256, 256, 0, stream>>>(bih, bhh, bias);
  hipMemcpyAsync(cst, c0, (size_t)BATCH * HID * 4, hipMemcpyDeviceToDevice, stream);
  hipMemsetAsync(bar, 0, 4 * 64 * sizeof(unsigned), stream);

  for (int chunk = 0; chunk < SEQ / TC; ++chunk) {
    int t0 = chunk * TC;
    gemm_xproj<<<dim3(BATCH, GATES / 128), 256, 0, stream>>>(x_b, Wih_b, bias, xp, t0);
    lstm_recur<<<dim3(64, 4), 256, 0, stream>>>(Whh_b, xp, hb0, hb1, cst, out, bar, t0);
  }
}